// Round 2
// baseline (119.585 us; speedup 1.0000x reference)
//
#include <hip/hip_runtime.h>
#include <math.h>

#define N_NODES 1024
#define N_EVAL 131072
#define NUM_POLES 8
#define PI_D 3.14159265358979323846

// ============================================================================
// V3: scalar node stream + 4 points/thread.
//
// V2 proved the node stream scalarizes (SGPR=80, VGPR=20) but stayed
// latency-bound (VALUBusy 21%): each s_load batch of 8-16 nodes fed only
// ~150-300cy of VALU against a ~300cy scalar-load round trip, and lockstep
// waves all stall on the same loads.
//
// Fix: amortize. Each thread evaluates 4 points -> 16 VALU ops per node
// loaded (4 sub + 4 rcp + 8 fma), ~600cy compute per 8-node batch >> load
// latency. Block = 512 thr = 8 waves; each wave owns a 128-node chunk for
// the block's 256 points; grid = 512 blocks = 16 waves/CU = 4 waves/SIMD
// for TLP on top of the 8 independent FMA chains/thread.
//
//  - setup_kernel: closed-form barycentric weights (fp64, once) into d_ws:
//    ws[0..1024)=nodes, [1024..2048)=w, [2048..3072)=w*v. For Chebyshev pts
//    of the 2nd kind, 1/prod_{i!=j}(x_j-x_i) = (-1)^j*delta_j*2^(n-1)/n;
//    uniform positive scalings cancel in num/den.
//  - eval kernel hot loop: pure VALU with SGPR operands, no LDS/barrier/
//    lgkmcnt dependency. 8 wave-partials per point reduced via LDS, divide,
//    rare exact-hit NaN fix-up (reference: exact-hit column reduces to
//    sum(hit w*v)/sum(hit w)).
// ============================================================================

__global__ __launch_bounds__(256) void setup_kernel(
    const float* __restrict__ values,
    const float* __restrict__ poles_real,
    const float* __restrict__ poles_imag,
    float* __restrict__ ws) {
    const int j = blockIdx.x * 256 + threadIdx.x;
    const double nd = cos(PI_D * (double)j / (double)(N_NODES - 1));
    double prod = (j == 0 || j == N_NODES - 1) ? 0.5 : 1.0;
#pragma unroll
    for (int m = 0; m < NUM_POLES; ++m) {
        const double dr = nd - (double)poles_real[m];
        const double di = (double)poles_imag[m];
        prod *= dr * dr + di * di;
    }
    if (j & 1) prod = -prod;
    ws[j]        = (float)nd;
    ws[j + 1024] = (float)prod;
    ws[j + 2048] = (float)(prod * (double)values[j]);
}

__global__ __launch_bounds__(512, 4) void eval_scalar4_kernel(
    const float* __restrict__ x_eval,
    const float* __restrict__ ws,
    float* __restrict__ out) {
    __shared__ float2 s_red[8][256];

    const int t = threadIdx.x;
    const int lane = t & 63;
    // Force wave-uniformity so the node-stream addresses scalarize (s_load).
    const int wid = __builtin_amdgcn_readfirstlane(t >> 6);
    const int pbase = blockIdx.x * 256;

    const float x0 = x_eval[pbase + lane];
    const float x1 = x_eval[pbase + 64 + lane];
    const float x2 = x_eval[pbase + 128 + lane];
    const float x3 = x_eval[pbase + 192 + lane];

    const float* __restrict__ nn = ws + wid * 128;
    const float* __restrict__ wq = ws + 1024 + wid * 128;
    const float* __restrict__ vq = ws + 2048 + wid * 128;

    float a0 = 0.0f, b0 = 0.0f, a1 = 0.0f, b1 = 0.0f;
    float a2 = 0.0f, b2 = 0.0f, a3 = 0.0f, b3 = 0.0f;

    // 16 batches of 8 nodes; each batch: 3x s_load_dwordx8 feeding
    // 8 nodes x 4 points x 4 ops = 128 VALU instructions (~600cy).
#pragma unroll 2
    for (int j = 0; j < 128; j += 8) {
#pragma unroll
        for (int k = 0; k < 8; ++k) {
            const float n = nn[j + k];
            const float w = wq[j + k];
            const float v = vq[j + k];
            const float d0 = x0 - n;
            const float d1 = x1 - n;
            const float d2 = x2 - n;
            const float d3 = x3 - n;
            const float r0 = __builtin_amdgcn_rcpf(d0);
            const float r1 = __builtin_amdgcn_rcpf(d1);
            const float r2 = __builtin_amdgcn_rcpf(d2);
            const float r3 = __builtin_amdgcn_rcpf(d3);
            a0 = fmaf(v, r0, a0); b0 = fmaf(w, r0, b0);
            a1 = fmaf(v, r1, a1); b1 = fmaf(w, r1, b1);
            a2 = fmaf(v, r2, a2); b2 = fmaf(w, r2, b2);
            a3 = fmaf(v, r3, a3); b3 = fmaf(w, r3, b3);
        }
    }

    s_red[wid][lane]       = make_float2(a0, b0);
    s_red[wid][lane + 64]  = make_float2(a1, b1);
    s_red[wid][lane + 128] = make_float2(a2, b2);
    s_red[wid][lane + 192] = make_float2(a3, b3);
    __syncthreads();

    if (t < 256) {
        float num = 0.0f, den = 0.0f;
#pragma unroll
        for (int w = 0; w < 8; ++w) {
            const float2 p = s_red[w][t];
            num += p.x;
            den += p.y;
        }
        float res = num / den;
        if (__builtin_expect(__builtin_isnan(res), 0)) {
            const float xx = x_eval[pbase + t];
            float hn = 0.0f, hd = 0.0f;
            for (int jj = 0; jj < N_NODES; ++jj) {
                if (ws[jj] == xx) { hn += ws[2048 + jj]; hd += ws[1024 + jj]; }
            }
            res = hn / hd;
        }
        out[pbase + t] = res;
    }
}

// ============================================================================
// Fallback (verified round-0 kernel) if the harness workspace is too small.
// ============================================================================
__global__ __launch_bounds__(512, 4) void eval_kernel_fused(
    const float* __restrict__ x_eval,
    const float* __restrict__ values,
    const float* __restrict__ poles_real,
    const float* __restrict__ poles_imag,
    float* __restrict__ out) {
    __shared__ __align__(16) float s_n[N_NODES];
    __shared__ __align__(16) float s_w[N_NODES];
    __shared__ __align__(16) float s_v[N_NODES];
    __shared__ float2 s_r[8][256];

    const int t = threadIdx.x;

#pragma unroll
    for (int h = 0; h < 2; ++h) {
        const int j = t + h * 512;
        const double nd = cos(PI_D * (double)j / (double)(N_NODES - 1));
        double prod = (j == 0 || j == N_NODES - 1) ? 0.5 : 1.0;
#pragma unroll
        for (int m = 0; m < NUM_POLES; ++m) {
            const double dr = nd - (double)poles_real[m];
            const double di = (double)poles_imag[m];
            prod *= dr * dr + di * di;
        }
        if (j & 1) prod = -prod;
        s_n[j] = (float)nd;
        s_w[j] = (float)prod;
        s_v[j] = (float)(prod * (double)values[j]);
    }
    __syncthreads();

    const int lane = t & 63;
    const int wid  = t >> 6;
    const int pbase = blockIdx.x * 256;
    const float x0 = x_eval[pbase + lane];
    const float x1 = x_eval[pbase + 64 + lane];
    const float x2 = x_eval[pbase + 128 + lane];
    const float x3 = x_eval[pbase + 192 + lane];

    const float4* n4 = (const float4*)s_n + wid * 32;
    const float4* w4 = (const float4*)s_w + wid * 32;
    const float4* v4 = (const float4*)s_v + wid * 32;

    float a0 = 0.0f, b0 = 0.0f, a1 = 0.0f, b1 = 0.0f;
    float a2 = 0.0f, b2 = 0.0f, a3 = 0.0f, b3 = 0.0f;

#define NODE(C)                                                            \
    {                                                                      \
        const float d0 = x0 - an.C;                                        \
        const float d1 = x1 - an.C;                                        \
        const float d2 = x2 - an.C;                                        \
        const float d3 = x3 - an.C;                                        \
        const float r0 = __builtin_amdgcn_rcpf(d0);                        \
        const float r1 = __builtin_amdgcn_rcpf(d1);                        \
        const float r2 = __builtin_amdgcn_rcpf(d2);                        \
        const float r3 = __builtin_amdgcn_rcpf(d3);                        \
        a0 = fmaf(av.C, r0, a0); b0 = fmaf(aw.C, r0, b0);                  \
        a1 = fmaf(av.C, r1, a1); b1 = fmaf(aw.C, r1, b1);                  \
        a2 = fmaf(av.C, r2, a2); b2 = fmaf(aw.C, r2, b2);                  \
        a3 = fmaf(av.C, r3, a3); b3 = fmaf(aw.C, r3, b3);                  \
    }

#pragma unroll 4
    for (int q = 0; q < 32; ++q) {
        const float4 an = n4[q];
        const float4 aw = w4[q];
        const float4 av = v4[q];
        NODE(x) NODE(y) NODE(z) NODE(w)
    }
#undef NODE

    s_r[wid][lane]       = make_float2(a0, b0);
    s_r[wid][lane + 64]  = make_float2(a1, b1);
    s_r[wid][lane + 128] = make_float2(a2, b2);
    s_r[wid][lane + 192] = make_float2(a3, b3);
    __syncthreads();

    if (t < 256) {
        float nn = 0.0f, dd = 0.0f;
#pragma unroll
        for (int w = 0; w < 8; ++w) {
            const float2 pr = s_r[w][t];
            nn += pr.x;
            dd += pr.y;
        }
        float res = nn / dd;
        if (__builtin_expect(__builtin_isnan(res), 0)) {
            const float x = x_eval[pbase + t];
            float hn = 0.0f, hd = 0.0f;
            for (int j = 0; j < N_NODES; ++j) {
                if (s_n[j] == x) { hn += s_v[j]; hd += s_w[j]; }
            }
            res = hn / hd;
        }
        out[pbase + t] = res;
    }
}

extern "C" void kernel_launch(void* const* d_in, const int* in_sizes, int n_in,
                              void* d_out, int out_size, void* d_ws, size_t ws_size,
                              hipStream_t stream) {
    const float* x_eval     = (const float*)d_in[0];
    const float* values     = (const float*)d_in[1];
    const float* poles_real = (const float*)d_in[2];
    const float* poles_imag = (const float*)d_in[3];
    float* out = (float*)d_out;

    if (ws_size >= 3 * N_NODES * sizeof(float)) {
        float* ws = (float*)d_ws;
        setup_kernel<<<N_NODES / 256, 256, 0, stream>>>(values, poles_real,
                                                        poles_imag, ws);
        eval_scalar4_kernel<<<N_EVAL / 256, 512, 0, stream>>>(x_eval, ws, out);
    } else {
        eval_kernel_fused<<<N_EVAL / 256, 512, 0, stream>>>(
            x_eval, values, poles_real, poles_imag, out);
    }
}